// Round 1
// baseline (7895.893 us; speedup 1.0000x reference)
//
#include <hip/hip_runtime.h>

// Problem constants (fixed by the reference):
//   N0=200000, N1=50000, N2=10000, E0=1600000, E1=320000
//   IN_CH=256, HID=256, OUT=128
// All row counts divide the tile sizes exactly (N1/16=3125, N2/16=625,
// E0/4, E1/4 integral), so row guards are omitted in the GEMMs.

#define ROWSP 20  // 16 rows + 4 pad (keeps 16B alignment for b128 LDS reads,
                  // breaks the 32-way write conflict a pad of 0 would give)

// ---------------------------------------------------------------------------
// Edge scatter: one 64-lane wave per edge. Each lane does a float4 gather from
// the source row and 4 global fp32 atomic adds into agg[dst]. Lane 0 bumps the
// degree counter.
// ---------------------------------------------------------------------------
__global__ __launch_bounds__(256) void scatter_kernel(
    const float* __restrict__ xsrc,  // [*, 256]
    const int* __restrict__ src,
    const int* __restrict__ dst,
    float* __restrict__ agg,         // [n_dst, 256] (pre-zeroed)
    float* __restrict__ cnt,         // [n_dst]      (pre-zeroed)
    int E)
{
    int e = blockIdx.x * 4 + (threadIdx.x >> 6);
    if (e >= E) return;
    int lane = threadIdx.x & 63;
    int s = src[e];
    int d = dst[e];
    float4 v = ((const float4*)(xsrc + (size_t)s * 256))[lane];
    float* a = agg + (size_t)d * 256 + lane * 4;
    atomicAdd(a + 0, v.x);
    atomicAdd(a + 1, v.y);
    atomicAdd(a + 2, v.z);
    atomicAdd(a + 3, v.w);
    if (lane == 0) atomicAdd(cnt + d, 1.0f);
}

// ---------------------------------------------------------------------------
// Fused layer-0 GEMM:  h = relu( (agg/cnt)@W_l + x@W_r + 0.25*attr[batch]@W_a
//                                + b_l + 0.25*b_a )
// Block = 256 threads, tile = 16 rows x 256 cols. A^T staged in LDS per
// 256-wide K segment (3 segments: mean | x_dst | scaled attr). Each thread
// owns one output column j=tid and 16 rows in registers. A reads from LDS are
// same-address broadcasts (conflict-free); W reads are fully coalesced and
// L2-resident (W is 768 KB total).
// ---------------------------------------------------------------------------
__global__ __launch_bounds__(256) void gemm0_kernel(
    const float* __restrict__ agg,   // [N1,256]
    const float* __restrict__ cnt,   // [N1]
    const float* __restrict__ x,     // [N0,256] (x_dst = first N1 rows)
    const float* __restrict__ attr,  // [N0,256]
    const int* __restrict__ batch,   // [N1]
    const float* __restrict__ Wl, const float* __restrict__ bl,
    const float* __restrict__ Wr,
    const float* __restrict__ Wa, const float* __restrict__ ba,
    float* __restrict__ hout)        // [N1,256]
{
    __shared__ float at[256 * ROWSP];
    const int tid = threadIdx.x;
    const int row0 = blockIdx.x * 16;

    float acc[16];
#pragma unroll
    for (int r = 0; r < 16; r++) acc[r] = 0.f;

    for (int seg = 0; seg < 3; seg++) {
        // stage A^T: at[k*ROWSP + r], k = tid
#pragma unroll
        for (int r = 0; r < 16; r++) {
            int i = row0 + r;
            float v;
            if (seg == 0) {
                float inv = 1.0f / fmaxf(cnt[i], 1.0f);
                v = agg[(size_t)i * 256 + tid] * inv;
            } else if (seg == 1) {
                v = x[(size_t)i * 256 + tid];
            } else {
                v = 0.25f * attr[(size_t)batch[i] * 256 + tid];
            }
            at[tid * ROWSP + r] = v;
        }
        __syncthreads();

        const float* __restrict__ W = (seg == 0) ? Wl : (seg == 1) ? Wr : Wa;
        for (int k = 0; k < 256; k++) {
            float wv = W[k * 256 + tid];
            const float* arow = &at[k * ROWSP];
#pragma unroll
            for (int r = 0; r < 16; r++)
                acc[r] = fmaf(arow[r], wv, acc[r]);
        }
        __syncthreads();
    }

#pragma unroll
    for (int r = 0; r < 16; r++) {
        float o = acc[r] + bl[tid] + 0.25f * ba[tid];
        hout[(size_t)(row0 + r) * 256 + tid] = fmaxf(o, 0.f);
    }
}

// ---------------------------------------------------------------------------
// Fused layer-1 GEMM: same structure, N=128 output cols. 256 threads:
// j = tid&127, row-half rh = tid>>7 (each thread does 8 of the 16 rows).
// ---------------------------------------------------------------------------
__global__ __launch_bounds__(256) void gemm1_kernel(
    const float* __restrict__ agg,   // [N2,256]
    const float* __restrict__ cnt,   // [N2]
    const float* __restrict__ h,     // [N1,256] (x_dst = first N2 rows)
    const float* __restrict__ attr,  // [N0,256]
    const int* __restrict__ batch,   // [N2]
    const float* __restrict__ Wl, const float* __restrict__ bl,
    const float* __restrict__ Wr,
    const float* __restrict__ Wa, const float* __restrict__ ba,
    float* __restrict__ out)         // [N2,128]
{
    __shared__ float at[256 * ROWSP];
    const int tid = threadIdx.x;
    const int row0 = blockIdx.x * 16;
    const int j = tid & 127;
    const int rh = tid >> 7;  // rows rh*8 .. rh*8+7

    float acc[8];
#pragma unroll
    for (int r = 0; r < 8; r++) acc[r] = 0.f;

    for (int seg = 0; seg < 3; seg++) {
#pragma unroll
        for (int r = 0; r < 16; r++) {
            int i = row0 + r;
            float v;
            if (seg == 0) {
                float inv = 1.0f / fmaxf(cnt[i], 1.0f);
                v = agg[(size_t)i * 256 + tid] * inv;
            } else if (seg == 1) {
                v = h[(size_t)i * 256 + tid];
            } else {
                v = 0.25f * attr[(size_t)batch[i] * 256 + tid];
            }
            at[tid * ROWSP + r] = v;
        }
        __syncthreads();

        const float* __restrict__ W = (seg == 0) ? Wl : (seg == 1) ? Wr : Wa;
        for (int k = 0; k < 256; k++) {
            float wv = W[k * 128 + j];
            const float* arow = &at[k * ROWSP + rh * 8];
#pragma unroll
            for (int r = 0; r < 8; r++)
                acc[r] = fmaf(arow[r], wv, acc[r]);
        }
        __syncthreads();
    }

#pragma unroll
    for (int r = 0; r < 8; r++) {
        float o = acc[r] + bl[j] + 0.25f * ba[j];
        out[(size_t)(row0 + rh * 8 + r) * 128 + j] = fmaxf(o, 0.f);
    }
}

// ---------------------------------------------------------------------------
// Launch
// ---------------------------------------------------------------------------
extern "C" void kernel_launch(void* const* d_in, const int* in_sizes, int n_in,
                              void* d_out, int out_size, void* d_ws, size_t ws_size,
                              hipStream_t stream) {
    const float* x     = (const float*)d_in[0];
    const float* attr  = (const float*)d_in[1];
    const int* src0    = (const int*)d_in[2];
    const int* dst0    = (const int*)d_in[3];
    const int* src1    = (const int*)d_in[4];
    const int* dst1    = (const int*)d_in[5];
    const int* batch0  = (const int*)d_in[6];
    const int* batch1  = (const int*)d_in[7];
    const float* W_l0  = (const float*)d_in[8];
    const float* b_l0  = (const float*)d_in[9];
    const float* W_r0  = (const float*)d_in[10];
    const float* W_l1  = (const float*)d_in[11];
    const float* b_l1  = (const float*)d_in[12];
    const float* W_r1  = (const float*)d_in[13];
    const float* W_a0  = (const float*)d_in[14];
    const float* b_a0  = (const float*)d_in[15];
    const float* W_a1  = (const float*)d_in[16];
    const float* b_a1  = (const float*)d_in[17];
    float* out = (float*)d_out;

    const int E0 = in_sizes[2];
    const int E1 = in_sizes[4];
    const int N1 = in_sizes[6];   // 50000
    const int N2 = in_sizes[7];   // 10000

    // workspace layout (floats)
    float* ws = (float*)d_ws;
    float* agg0 = ws;                         // N1*256 = 12,800,000
    float* cnt0 = agg0 + (size_t)N1 * 256;    // N1
    float* agg1 = cnt0 + N1;                  // N2*256 = 2,560,000
    float* cnt1 = agg1 + (size_t)N2 * 256;    // N2
    float* h    = cnt1 + N2;                  // N1*256
    size_t zero_floats = (size_t)N1 * 256 + N1 + (size_t)N2 * 256 + N2;

    hipMemsetAsync(d_ws, 0, zero_floats * sizeof(float), stream);

    // layer 0
    scatter_kernel<<<E0 / 4, 256, 0, stream>>>(x, src0, dst0, agg0, cnt0, E0);
    gemm0_kernel<<<N1 / 16, 256, 0, stream>>>(agg0, cnt0, x, attr, batch0,
                                              W_l0, b_l0, W_r0, W_a0, b_a0, h);
    // layer 1
    scatter_kernel<<<E1 / 4, 256, 0, stream>>>(h, src1, dst1, agg1, cnt1, E1);
    gemm1_kernel<<<N2 / 16, 256, 0, stream>>>(agg1, cnt1, h, attr, batch1,
                                              W_l1, b_l1, W_r1, W_a1, b_a1, out);
}

// Round 2
// 2094.254 us; speedup vs baseline: 3.7703x; 3.7703x over previous
//
#include <hip/hip_runtime.h>

// Problem constants (fixed by the reference):
//   N0=200000, N1=50000, N2=10000, E0=1600000, E1=320000
//   IN_CH=256, HID=256, OUT=128
//
// Round 2: replace atomic scatter (6.45 GB of HBM atomic write traffic, 5.4ms)
// with device-built CSR + one-wave-per-row gather aggregation (reads only).

#define ROWSP 20  // 16 rows + 4 pad for the GEMM A^T tiles

// ---------------------------------------------------------------------------
// CSR build step 1: degree histogram. 1.6M int atomics over 50k counters.
// ---------------------------------------------------------------------------
__global__ __launch_bounds__(256) void count_kernel(
    const int* __restrict__ dst, int* __restrict__ deg, int E)
{
    int e = blockIdx.x * 256 + threadIdx.x;
    if (e < E) atomicAdd(&deg[dst[e]], 1);
}

// ---------------------------------------------------------------------------
// CSR build step 2: single-block exclusive scan (n <= 50000).
// Writes rowptr[0..n]; overwrites deg[i] with the running offset so it can
// serve as the atomic cursor ("pos") for the bucket pass.
// ---------------------------------------------------------------------------
__global__ __launch_bounds__(256) void scan_kernel(
    int* __restrict__ deg, int* __restrict__ rowptr, int n)
{
    __shared__ int part[256];
    const int t = threadIdx.x;
    const int chunk = (n + 255) / 256;
    const int lo = t * chunk;
    const int hi = min(lo + chunk, n);
    int s = 0;
    for (int i = lo; i < hi; i++) s += deg[i];
    part[t] = s;
    __syncthreads();
    if (t == 0) {
        int acc = 0;
        for (int i = 0; i < 256; i++) { int v = part[i]; part[i] = acc; acc += v; }
        rowptr[n] = acc;
    }
    __syncthreads();
    int acc = part[t];
    for (int i = lo; i < hi; i++) {
        int d = deg[i];
        rowptr[i] = acc;
        deg[i] = acc;   // becomes the bucket cursor
        acc += d;
    }
}

// ---------------------------------------------------------------------------
// CSR build step 3: bucket the src ids by dst.
// ---------------------------------------------------------------------------
__global__ __launch_bounds__(256) void bucket_kernel(
    const int* __restrict__ src, const int* __restrict__ dst,
    int* __restrict__ pos, int* __restrict__ bsrc, int E)
{
    int e = blockIdx.x * 256 + threadIdx.x;
    if (e < E) {
        int p = atomicAdd(&pos[dst[e]], 1);
        bsrc[p] = src[e];
    }
}

// ---------------------------------------------------------------------------
// Aggregation: one 64-lane wave per destination row. Each lane owns 4 of the
// 256 feature channels (float4). Coalesced 1KB reads per edge, one 1KB write
// per row, mean computed in-register (divide folded in here, not the GEMM).
// ---------------------------------------------------------------------------
__global__ __launch_bounds__(256) void aggregate_kernel(
    const float* __restrict__ xsrc,     // [*, 256]
    const int* __restrict__ rowptr,     // [n+1]
    const int* __restrict__ bsrc,       // [E]
    float* __restrict__ mean,           // [n, 256]
    int n)
{
    int row = blockIdx.x * 4 + (threadIdx.x >> 6);
    if (row >= n) return;
    const int lane = threadIdx.x & 63;
    const int beg = rowptr[row];
    const int end = rowptr[row + 1];

    float4 a0 = {0.f, 0.f, 0.f, 0.f};
    float4 a1 = {0.f, 0.f, 0.f, 0.f};
    int e = beg;
    for (; e + 1 < end; e += 2) {
        int s0 = bsrc[e];
        int s1 = bsrc[e + 1];
        float4 v0 = ((const float4*)(xsrc + (size_t)s0 * 256))[lane];
        float4 v1 = ((const float4*)(xsrc + (size_t)s1 * 256))[lane];
        a0.x += v0.x; a0.y += v0.y; a0.z += v0.z; a0.w += v0.w;
        a1.x += v1.x; a1.y += v1.y; a1.z += v1.z; a1.w += v1.w;
    }
    if (e < end) {
        int s0 = bsrc[e];
        float4 v0 = ((const float4*)(xsrc + (size_t)s0 * 256))[lane];
        a0.x += v0.x; a0.y += v0.y; a0.z += v0.z; a0.w += v0.w;
    }
    float inv = 1.0f / fmaxf((float)(end - beg), 1.0f);
    float4 r;
    r.x = (a0.x + a1.x) * inv;
    r.y = (a0.y + a1.y) * inv;
    r.z = (a0.z + a1.z) * inv;
    r.w = (a0.w + a1.w) * inv;
    ((float4*)(mean + (size_t)row * 256))[lane] = r;
}

// ---------------------------------------------------------------------------
// Fused layer-0 GEMM:  h = relu( mean@W_l + x@W_r + 0.25*attr[batch]@W_a
//                                + b_l + 0.25*b_a )
// Block = 256 threads, tile = 16 rows x 256 cols, K = 3x256.
// ---------------------------------------------------------------------------
__global__ __launch_bounds__(256) void gemm0_kernel(
    const float* __restrict__ mean,  // [N1,256]
    const float* __restrict__ x,     // [N0,256] (x_dst = first N1 rows)
    const float* __restrict__ attr,  // [N0,256]
    const int* __restrict__ batch,   // [N1]
    const float* __restrict__ Wl, const float* __restrict__ bl,
    const float* __restrict__ Wr,
    const float* __restrict__ Wa, const float* __restrict__ ba,
    float* __restrict__ hout)        // [N1,256]
{
    __shared__ float at[256 * ROWSP];
    const int tid = threadIdx.x;
    const int row0 = blockIdx.x * 16;

    float acc[16];
#pragma unroll
    for (int r = 0; r < 16; r++) acc[r] = 0.f;

    for (int seg = 0; seg < 3; seg++) {
#pragma unroll
        for (int r = 0; r < 16; r++) {
            int i = row0 + r;
            float v;
            if (seg == 0) {
                v = mean[(size_t)i * 256 + tid];
            } else if (seg == 1) {
                v = x[(size_t)i * 256 + tid];
            } else {
                v = 0.25f * attr[(size_t)batch[i] * 256 + tid];
            }
            at[tid * ROWSP + r] = v;
        }
        __syncthreads();

        const float* __restrict__ W = (seg == 0) ? Wl : (seg == 1) ? Wr : Wa;
        for (int k = 0; k < 256; k++) {
            float wv = W[k * 256 + tid];
            const float* arow = &at[k * ROWSP];
#pragma unroll
            for (int r = 0; r < 16; r++)
                acc[r] = fmaf(arow[r], wv, acc[r]);
        }
        __syncthreads();
    }

#pragma unroll
    for (int r = 0; r < 16; r++) {
        float o = acc[r] + bl[tid] + 0.25f * ba[tid];
        hout[(size_t)(row0 + r) * 256 + tid] = fmaxf(o, 0.f);
    }
}

// ---------------------------------------------------------------------------
// Fused layer-1 GEMM: N=128 output cols; j = tid&127, row-half rh = tid>>7.
// ---------------------------------------------------------------------------
__global__ __launch_bounds__(256) void gemm1_kernel(
    const float* __restrict__ mean,  // [N2,256]
    const float* __restrict__ h,     // [N1,256] (x_dst = first N2 rows)
    const float* __restrict__ attr,  // [N0,256]
    const int* __restrict__ batch,   // [N2]
    const float* __restrict__ Wl, const float* __restrict__ bl,
    const float* __restrict__ Wr,
    const float* __restrict__ Wa, const float* __restrict__ ba,
    float* __restrict__ out)         // [N2,128]
{
    __shared__ float at[256 * ROWSP];
    const int tid = threadIdx.x;
    const int row0 = blockIdx.x * 16;
    const int j = tid & 127;
    const int rh = tid >> 7;

    float acc[8];
#pragma unroll
    for (int r = 0; r < 8; r++) acc[r] = 0.f;

    for (int seg = 0; seg < 3; seg++) {
#pragma unroll
        for (int r = 0; r < 16; r++) {
            int i = row0 + r;
            float v;
            if (seg == 0) {
                v = mean[(size_t)i * 256 + tid];
            } else if (seg == 1) {
                v = h[(size_t)i * 256 + tid];
            } else {
                v = 0.25f * attr[(size_t)batch[i] * 256 + tid];
            }
            at[tid * ROWSP + r] = v;
        }
        __syncthreads();

        const float* __restrict__ W = (seg == 0) ? Wl : (seg == 1) ? Wr : Wa;
        for (int k = 0; k < 256; k++) {
            float wv = W[k * 128 + j];
            const float* arow = &at[k * ROWSP + rh * 8];
#pragma unroll
            for (int r = 0; r < 8; r++)
                acc[r] = fmaf(arow[r], wv, acc[r]);
        }
        __syncthreads();
    }

#pragma unroll
    for (int r = 0; r < 8; r++) {
        float o = acc[r] + bl[j] + 0.25f * ba[j];
        out[(size_t)(row0 + rh * 8 + r) * 128 + j] = fmaxf(o, 0.f);
    }
}

// ---------------------------------------------------------------------------
// Launch
// ---------------------------------------------------------------------------
extern "C" void kernel_launch(void* const* d_in, const int* in_sizes, int n_in,
                              void* d_out, int out_size, void* d_ws, size_t ws_size,
                              hipStream_t stream) {
    const float* x     = (const float*)d_in[0];
    const float* attr  = (const float*)d_in[1];
    const int* src0    = (const int*)d_in[2];
    const int* dst0    = (const int*)d_in[3];
    const int* src1    = (const int*)d_in[4];
    const int* dst1    = (const int*)d_in[5];
    const int* batch0  = (const int*)d_in[6];
    const int* batch1  = (const int*)d_in[7];
    const float* W_l0  = (const float*)d_in[8];
    const float* b_l0  = (const float*)d_in[9];
    const float* W_r0  = (const float*)d_in[10];
    const float* W_l1  = (const float*)d_in[11];
    const float* b_l1  = (const float*)d_in[12];
    const float* W_r1  = (const float*)d_in[13];
    const float* W_a0  = (const float*)d_in[14];
    const float* b_a0  = (const float*)d_in[15];
    const float* W_a1  = (const float*)d_in[16];
    const float* b_a1  = (const float*)d_in[17];
    float* out = (float*)d_out;

    const int E0 = in_sizes[2];   // 1600000
    const int E1 = in_sizes[4];   // 320000
    const int N1 = in_sizes[6];   // 50000
    const int N2 = in_sizes[7];   // 10000

    // workspace layout (ws_size >= ~113MB, proven by round-0 usage)
    float* ws   = (float*)d_ws;
    float* mean0 = ws;                               // N1*256 floats (51.2MB)
    float* h     = mean0 + (size_t)N1 * 256;         // N1*256 floats (51.2MB)
    int*   ibase = (int*)(h + (size_t)N1 * 256);
    int*   bsrc0   = ibase;                          // E0
    int*   rowptr0 = bsrc0 + E0;                     // N1+1
    int*   deg0    = rowptr0 + N1 + 1;               // N1 (doubles as cursor)
    int*   bsrc1   = deg0 + N1;                      // E1
    int*   rowptr1 = bsrc1 + E1;                     // N2+1
    int*   deg1    = rowptr1 + N2 + 1;               // N2
    float* mean1 = mean0;                            // alias: free after gemm0

    // ---- layer 0 CSR + aggregate ----
    hipMemsetAsync(deg0, 0, (size_t)N1 * sizeof(int), stream);
    count_kernel<<<(E0 + 255) / 256, 256, 0, stream>>>(dst0, deg0, E0);
    scan_kernel<<<1, 256, 0, stream>>>(deg0, rowptr0, N1);
    bucket_kernel<<<(E0 + 255) / 256, 256, 0, stream>>>(src0, dst0, deg0, bsrc0, E0);
    aggregate_kernel<<<(N1 + 3) / 4, 256, 0, stream>>>(x, rowptr0, bsrc0, mean0, N1);

    gemm0_kernel<<<N1 / 16, 256, 0, stream>>>(mean0, x, attr, batch0,
                                              W_l0, b_l0, W_r0, W_a0, b_a0, h);

    // ---- layer 1 CSR + aggregate (mean1 aliases mean0: only after gemm0) ----
    hipMemsetAsync(deg1, 0, (size_t)N2 * sizeof(int), stream);
    count_kernel<<<(E1 + 255) / 256, 256, 0, stream>>>(dst1, deg1, E1);
    scan_kernel<<<1, 256, 0, stream>>>(deg1, rowptr1, N2);
    bucket_kernel<<<(E1 + 255) / 256, 256, 0, stream>>>(src1, dst1, deg1, bsrc1, E1);
    aggregate_kernel<<<(N2 + 3) / 4, 256, 0, stream>>>(h, rowptr1, bsrc1, mean1, N2);

    gemm1_kernel<<<N2 / 16, 256, 0, stream>>>(mean1, h, attr, batch1,
                                              W_l1, b_l1, W_r1, W_a1, b_a1, out);
}

// Round 3
// 1091.765 us; speedup vs baseline: 7.2322x; 1.9182x over previous
//
#include <hip/hip_runtime.h>

// Problem constants (fixed by the reference):
//   N0=200000, N1=50000, N2=10000, E0=1600000, E1=320000
//   IN_CH=256, HID=256, OUT=128,  K = 3*256 = 768
//
// Round 3: bf16 MFMA GEMMs (16x16x32, 128x128 tile, 4 waves x 4x4 frags).
// A packed bf16 [Mpad][768] = [mean | x_dst | 0.25*attr[batch]]; W transposed
// to [N][768] bf16 so both LDS stages are coalesced. h kept bf16.
// Mpad0 = 391*128 = 50048, Mpad1 = 79*128 = 10112 (stores guarded by M).

typedef __attribute__((ext_vector_type(8))) short short8;
typedef __attribute__((ext_vector_type(4))) float float4v;

__device__ __forceinline__ unsigned short f2bf(float f) {
    union { float f; unsigned int u; } c; c.f = f;
    unsigned int r = (c.u + 0x7FFFu + ((c.u >> 16) & 1u)) >> 16;  // RNE
    return (unsigned short)r;
}
__device__ __forceinline__ float bf2f(unsigned short u) {
    union { unsigned int u; float f; } c; c.u = ((unsigned int)u) << 16;
    return c.f;
}

// ---------------------------------------------------------------------------
// CSR build (unchanged from round 2)
// ---------------------------------------------------------------------------
__global__ __launch_bounds__(256) void count_kernel(
    const int* __restrict__ dst, int* __restrict__ deg, int E)
{
    int e = blockIdx.x * 256 + threadIdx.x;
    if (e < E) atomicAdd(&deg[dst[e]], 1);
}

__global__ __launch_bounds__(256) void scan_kernel(
    int* __restrict__ deg, int* __restrict__ rowptr, int n)
{
    __shared__ int part[256];
    const int t = threadIdx.x;
    const int chunk = (n + 255) / 256;
    const int lo = t * chunk;
    const int hi = min(lo + chunk, n);
    int s = 0;
    for (int i = lo; i < hi; i++) s += deg[i];
    part[t] = s;
    __syncthreads();
    if (t == 0) {
        int acc = 0;
        for (int i = 0; i < 256; i++) { int v = part[i]; part[i] = acc; acc += v; }
        rowptr[n] = acc;
    }
    __syncthreads();
    int acc = part[t];
    for (int i = lo; i < hi; i++) {
        int d = deg[i];
        rowptr[i] = acc;
        deg[i] = acc;   // becomes the bucket cursor
        acc += d;
    }
}

__global__ __launch_bounds__(256) void bucket_kernel(
    const int* __restrict__ src, const int* __restrict__ dst,
    int* __restrict__ pos, int* __restrict__ bsrc, int E)
{
    int e = blockIdx.x * 256 + threadIdx.x;
    if (e < E) {
        int p = atomicAdd(&pos[dst[e]], 1);
        bsrc[p] = src[e];
    }
}

// ---------------------------------------------------------------------------
// Aggregation, fp32 source -> bf16 mean written at pitch 768 (seg 0 of abuf).
// One wave per row; lane owns 4 of 256 channels.
// ---------------------------------------------------------------------------
__global__ __launch_bounds__(256) void agg_f32_kernel(
    const float* __restrict__ xsrc,     // [*, 256] fp32
    const int* __restrict__ rowptr,
    const int* __restrict__ bsrc,
    unsigned short* __restrict__ outp,  // bf16, row pitch `pitch`
    int pitch, int n)
{
    int row = blockIdx.x * 4 + (threadIdx.x >> 6);
    if (row >= n) return;
    const int lane = threadIdx.x & 63;
    const int beg = rowptr[row];
    const int end = rowptr[row + 1];

    float4 a0 = {0.f, 0.f, 0.f, 0.f};
    float4 a1 = {0.f, 0.f, 0.f, 0.f};
    int e = beg;
    for (; e + 1 < end; e += 2) {
        int s0 = bsrc[e];
        int s1 = bsrc[e + 1];
        float4 v0 = ((const float4*)(xsrc + (size_t)s0 * 256))[lane];
        float4 v1 = ((const float4*)(xsrc + (size_t)s1 * 256))[lane];
        a0.x += v0.x; a0.y += v0.y; a0.z += v0.z; a0.w += v0.w;
        a1.x += v1.x; a1.y += v1.y; a1.z += v1.z; a1.w += v1.w;
    }
    if (e < end) {
        int s0 = bsrc[e];
        float4 v0 = ((const float4*)(xsrc + (size_t)s0 * 256))[lane];
        a0.x += v0.x; a0.y += v0.y; a0.z += v0.z; a0.w += v0.w;
    }
    float inv = 1.0f / fmaxf((float)(end - beg), 1.0f);
    ushort4 r;
    r.x = f2bf((a0.x + a1.x) * inv);
    r.y = f2bf((a0.y + a1.y) * inv);
    r.z = f2bf((a0.z + a1.z) * inv);
    r.w = f2bf((a0.w + a1.w) * inv);
    *(ushort4*)(outp + (size_t)row * pitch + lane * 4) = r;
}

// Aggregation, bf16 source (h) -> bf16 mean at pitch 768.
__global__ __launch_bounds__(256) void agg_bf16_kernel(
    const unsigned short* __restrict__ hsrc,  // [*, 256] bf16
    const int* __restrict__ rowptr,
    const int* __restrict__ bsrc,
    unsigned short* __restrict__ outp,
    int pitch, int n)
{
    int row = blockIdx.x * 4 + (threadIdx.x >> 6);
    if (row >= n) return;
    const int lane = threadIdx.x & 63;
    const int beg = rowptr[row];
    const int end = rowptr[row + 1];

    float4 a0 = {0.f, 0.f, 0.f, 0.f};
    float4 a1 = {0.f, 0.f, 0.f, 0.f};
    int e = beg;
    for (; e + 1 < end; e += 2) {
        int s0 = bsrc[e];
        int s1 = bsrc[e + 1];
        ushort4 u0 = *(const ushort4*)(hsrc + (size_t)s0 * 256 + lane * 4);
        ushort4 u1 = *(const ushort4*)(hsrc + (size_t)s1 * 256 + lane * 4);
        a0.x += bf2f(u0.x); a0.y += bf2f(u0.y); a0.z += bf2f(u0.z); a0.w += bf2f(u0.w);
        a1.x += bf2f(u1.x); a1.y += bf2f(u1.y); a1.z += bf2f(u1.z); a1.w += bf2f(u1.w);
    }
    if (e < end) {
        int s0 = bsrc[e];
        ushort4 u0 = *(const ushort4*)(hsrc + (size_t)s0 * 256 + lane * 4);
        a0.x += bf2f(u0.x); a0.y += bf2f(u0.y); a0.z += bf2f(u0.z); a0.w += bf2f(u0.w);
    }
    float inv = 1.0f / fmaxf((float)(end - beg), 1.0f);
    ushort4 r;
    r.x = f2bf((a0.x + a1.x) * inv);
    r.y = f2bf((a0.y + a1.y) * inv);
    r.z = f2bf((a0.z + a1.z) * inv);
    r.w = f2bf((a0.w + a1.w) * inv);
    *(ushort4*)(outp + (size_t)row * pitch + lane * 4) = r;
}

// ---------------------------------------------------------------------------
// Pack seg1 (x_dst, fp32->bf16) and seg2 (0.25*attr[batch], fp32->bf16).
// ---------------------------------------------------------------------------
__global__ __launch_bounds__(256) void pack0_kernel(
    const float* __restrict__ x, const float* __restrict__ attr,
    const int* __restrict__ batch, unsigned short* __restrict__ abuf, int n)
{
    int row = blockIdx.x * 4 + (threadIdx.x >> 6);
    if (row >= n) return;
    const int lane = threadIdx.x & 63;
    float4 xv = ((const float4*)(x + (size_t)row * 256))[lane];
    int b = batch[row];
    float4 av = ((const float4*)(attr + (size_t)b * 256))[lane];
    unsigned short* dst = abuf + (size_t)row * 768;
    ushort4 r1; r1.x = f2bf(xv.x); r1.y = f2bf(xv.y); r1.z = f2bf(xv.z); r1.w = f2bf(xv.w);
    *(ushort4*)(dst + 256 + lane * 4) = r1;
    ushort4 r2; r2.x = f2bf(0.25f * av.x); r2.y = f2bf(0.25f * av.y);
    r2.z = f2bf(0.25f * av.z); r2.w = f2bf(0.25f * av.w);
    *(ushort4*)(dst + 512 + lane * 4) = r2;
}

// seg1 from bf16 h (straight copy), seg2 from fp32 attr gather.
__global__ __launch_bounds__(256) void pack1_kernel(
    const unsigned short* __restrict__ h, const float* __restrict__ attr,
    const int* __restrict__ batch, unsigned short* __restrict__ abuf, int n)
{
    int row = blockIdx.x * 4 + (threadIdx.x >> 6);
    if (row >= n) return;
    const int lane = threadIdx.x & 63;
    ushort4 hv = *(const ushort4*)(h + (size_t)row * 256 + lane * 4);
    int b = batch[row];
    float4 av = ((const float4*)(attr + (size_t)b * 256))[lane];
    unsigned short* dst = abuf + (size_t)row * 768;
    *(ushort4*)(dst + 256 + lane * 4) = hv;
    ushort4 r2; r2.x = f2bf(0.25f * av.x); r2.y = f2bf(0.25f * av.y);
    r2.z = f2bf(0.25f * av.z); r2.w = f2bf(0.25f * av.w);
    *(ushort4*)(dst + 512 + lane * 4) = r2;
}

// ---------------------------------------------------------------------------
// Weight transpose+cvt: Wt[n][k] (bf16, k contiguous), k = [Wl | Wr | Wa].
// Also combines bias: bias[n] = bl[n] + 0.25*ba[n]. grid = (3, N) x 256.
// (0.25 attr scale is applied to the A values in pack*, not to Wa.)
// ---------------------------------------------------------------------------
__global__ __launch_bounds__(256) void wcvt_kernel(
    const float* __restrict__ Wl, const float* __restrict__ Wr,
    const float* __restrict__ Wa, const float* __restrict__ bl,
    const float* __restrict__ ba, unsigned short* __restrict__ Wt,
    float* __restrict__ bias, int N)
{
    int k = blockIdx.x * 256 + threadIdx.x;  // 0..767
    int n = blockIdx.y;
    const float* W; int kk;
    if (k < 256)      { W = Wl; kk = k; }
    else if (k < 512) { W = Wr; kk = k - 256; }
    else              { W = Wa; kk = k - 512; }
    Wt[(size_t)n * 768 + k] = f2bf(W[(size_t)kk * N + n]);
    if (k == 0) bias[n] = bl[n] + 0.25f * ba[n];
}

// ---------------------------------------------------------------------------
// bf16 MFMA GEMM: C = relu(A @ Wt^T + bias).
// A: [Mpad][768] bf16. Wt: [N][768] bf16 (k contiguous). Block 256 thr =
// 4 waves, tile 128x128, BK=64 (2 mfma-K per frag). LDS rows padded to 72
// bf16 (144 B) -> fragment ds_read_b128 spreads all 32 banks (2-way = free).
// Frag layouts (HW-verified per guide): A[m=lane&15][k=quad*8+j],
// B[n=lane&15][k=quad*8+j], C col=lane&15, row=quad*4+reg.
// ---------------------------------------------------------------------------
template<bool OUT_BF16>
__global__ __launch_bounds__(256) void gemm_mfma_kernel(
    const unsigned short* __restrict__ A,   // [Mpad][768]
    const unsigned short* __restrict__ Wt,  // [N][768]
    const float* __restrict__ bias,         // [N]
    void* __restrict__ Cout, int M, int ldc)
{
    __shared__ unsigned short As[128 * 72];
    __shared__ unsigned short Bs[128 * 72];
    const int tid  = threadIdx.x;
    const int lane = tid & 63;
    const int wave = tid >> 6;
    const int lm   = lane & 15;
    const int quad = lane >> 4;
    const int wm   = (wave & 1) * 64;
    const int wn   = (wave >> 1) * 64;
    const int m0   = blockIdx.x * 128;
    const int n0   = blockIdx.y * 128;

    float4v acc[4][4];
#pragma unroll
    for (int i = 0; i < 4; i++)
#pragma unroll
        for (int j = 0; j < 4; j++)
            acc[i][j] = (float4v){0.f, 0.f, 0.f, 0.f};

    for (int kt = 0; kt < 768; kt += 64) {
        // stage 128x64 bf16 tiles of A and Wt (16B chunks, fully coalesced)
#pragma unroll
        for (int i = 0; i < 4; i++) {
            int c = i * 256 + tid;       // 0..1023
            int row = c >> 3;            // 0..127
            int col = (c & 7) * 8;       // 0..56
            *(uint4*)&As[row * 72 + col] =
                *(const uint4*)&A[(size_t)(m0 + row) * 768 + kt + col];
            *(uint4*)&Bs[row * 72 + col] =
                *(const uint4*)&Wt[(size_t)(n0 + row) * 768 + kt + col];
        }
        __syncthreads();

#pragma unroll
        for (int h = 0; h < 2; h++) {   // two K=32 sub-steps
            short8 a[4], b[4];
#pragma unroll
            for (int i = 0; i < 4; i++)
                a[i] = *(const short8*)&As[(wm + i * 16 + lm) * 72 + h * 32 + quad * 8];
#pragma unroll
            for (int j = 0; j < 4; j++)
                b[j] = *(const short8*)&Bs[(wn + j * 16 + lm) * 72 + h * 32 + quad * 8];
#pragma unroll
            for (int i = 0; i < 4; i++)
#pragma unroll
                for (int j = 0; j < 4; j++)
                    acc[i][j] = __builtin_amdgcn_mfma_f32_16x16x32_bf16(
                        a[i], b[j], acc[i][j], 0, 0, 0);
        }
        __syncthreads();
    }

    // epilogue: bias + relu, store (row-guarded for the padded M tail)
    float bcol[4];
#pragma unroll
    for (int j = 0; j < 4; j++) bcol[j] = bias[n0 + wn + j * 16 + lm];

#pragma unroll
    for (int i = 0; i < 4; i++) {
        int rbase = m0 + wm + i * 16 + quad * 4;
#pragma unroll
        for (int j = 0; j < 4; j++) {
            int col = n0 + wn + j * 16 + lm;
#pragma unroll
            for (int r = 0; r < 4; r++) {
                int row = rbase + r;
                if (row < M) {
                    float v = fmaxf(acc[i][j][r] + bcol[j], 0.f);
                    if (OUT_BF16)
                        ((unsigned short*)Cout)[(size_t)row * ldc + col] = f2bf(v);
                    else
                        ((float*)Cout)[(size_t)row * ldc + col] = v;
                }
            }
        }
    }
}

// ---------------------------------------------------------------------------
// Launch
// ---------------------------------------------------------------------------
extern "C" void kernel_launch(void* const* d_in, const int* in_sizes, int n_in,
                              void* d_out, int out_size, void* d_ws, size_t ws_size,
                              hipStream_t stream) {
    const float* x     = (const float*)d_in[0];
    const float* attr  = (const float*)d_in[1];
    const int* src0    = (const int*)d_in[2];
    const int* dst0    = (const int*)d_in[3];
    const int* src1    = (const int*)d_in[4];
    const int* dst1    = (const int*)d_in[5];
    const int* batch0  = (const int*)d_in[6];
    const int* batch1  = (const int*)d_in[7];
    const float* W_l0  = (const float*)d_in[8];
    const float* b_l0  = (const float*)d_in[9];
    const float* W_r0  = (const float*)d_in[10];
    const float* W_l1  = (const float*)d_in[11];
    const float* b_l1  = (const float*)d_in[12];
    const float* W_r1  = (const float*)d_in[13];
    const float* W_a0  = (const float*)d_in[14];
    const float* b_a0  = (const float*)d_in[15];
    const float* W_a1  = (const float*)d_in[16];
    const float* b_a1  = (const float*)d_in[17];
    float* out = (float*)d_out;

    const int E0 = in_sizes[2];   // 1600000
    const int E1 = in_sizes[4];   // 320000
    const int N1 = in_sizes[6];   // 50000
    const int N2 = in_sizes[7];   // 10000
    const int MP0 = 50048;        // 391*128
    const int MP1 = 10112;        // 79*128

    // workspace layout (~109.9 MB; round-1 proved >= 110.5 MB available)
    char* p = (char*)d_ws;
    unsigned short* abuf = (unsigned short*)p;      // [50048][768] bf16 (76.9MB)
    p += (size_t)MP0 * 768 * 2;                     // abuf1 [10112][768] aliases abuf
    unsigned short* h = (unsigned short*)p;         // [50048][256] bf16 (25.6MB)
    p += (size_t)MP0 * 256 * 2;
    unsigned short* Wt0 = (unsigned short*)p; p += (size_t)256 * 768 * 2;
    unsigned short* Wt1 = (unsigned short*)p; p += (size_t)128 * 768 * 2;
    float* bias0 = (float*)p; p += 256 * 4;
    float* bias1 = (float*)p; p += 128 * 4;
    int* bsrc0   = (int*)p;                         // E0 ints (6.4MB)
    int* rowptr0 = bsrc0 + E0;                      // N1+1
    int* deg0    = rowptr0 + N1 + 1;                // N1
    // layer-1 CSR aliases bsrc0's region (bsrc0 dead after agg_f32)
    int* bsrc1   = bsrc0;                           // E1
    int* rowptr1 = bsrc1 + E1;                      // N2+1
    int* deg1    = rowptr1 + N2 + 1;                // N2

    // ---- layer 0 ----
    hipMemsetAsync(deg0, 0, (size_t)N1 * sizeof(int), stream);
    count_kernel<<<(E0 + 255) / 256, 256, 0, stream>>>(dst0, deg0, E0);
    scan_kernel<<<1, 256, 0, stream>>>(deg0, rowptr0, N1);
    bucket_kernel<<<(E0 + 255) / 256, 256, 0, stream>>>(src0, dst0, deg0, bsrc0, E0);
    agg_f32_kernel<<<(N1 + 3) / 4, 256, 0, stream>>>(x, rowptr0, bsrc0, abuf, 768, N1);
    pack0_kernel<<<(N1 + 3) / 4, 256, 0, stream>>>(x, attr, batch0, abuf, N1);
    wcvt_kernel<<<dim3(3, 256), 256, 0, stream>>>(W_l0, W_r0, W_a0, b_l0, b_a0,
                                                  Wt0, bias0, 256);
    gemm_mfma_kernel<true><<<dim3(MP0 / 128, 2), 256, 0, stream>>>(
        abuf, Wt0, bias0, h, MP0, 256);

    // ---- layer 1 (CSR bufs alias bsrc0; abuf1 aliases abuf — both dead) ----
    hipMemsetAsync(deg1, 0, (size_t)N2 * sizeof(int), stream);
    count_kernel<<<(E1 + 255) / 256, 256, 0, stream>>>(dst1, deg1, E1);
    scan_kernel<<<1, 256, 0, stream>>>(deg1, rowptr1, N2);
    bucket_kernel<<<(E1 + 255) / 256, 256, 0, stream>>>(src1, dst1, deg1, bsrc1, E1);
    agg_bf16_kernel<<<(N2 + 3) / 4, 256, 0, stream>>>(h, rowptr1, bsrc1, abuf, 768, N2);
    pack1_kernel<<<(N2 + 3) / 4, 256, 0, stream>>>(h, attr, batch1, abuf, N2);
    wcvt_kernel<<<dim3(3, 128), 256, 0, stream>>>(W_l1, W_r1, W_a1, b_l1, b_a1,
                                                  Wt1, bias1, 128);
    gemm_mfma_kernel<false><<<dim3(MP1 / 128, 1), 256, 0, stream>>>(
        abuf, Wt1, bias1, out, N2, 128);
}

// Round 4
// 973.640 us; speedup vs baseline: 8.1097x; 1.1213x over previous
//
#include <hip/hip_runtime.h>

// Problem constants (fixed by the reference):
//   N0=200000, N1=50000, N2=10000, E0=1600000, E1=320000
//   IN_CH=256, HID=256, OUT=128,  K = 3*256 = 768
//
// Round 4: parallelize the CSR build (the old single-block scan was a
// serial ~200us stage on one CU), add 4-edge ILP to the row-gather
// aggregation, vectorize count/bucket to 4 edges/thread.

typedef __attribute__((ext_vector_type(8))) short short8;
typedef __attribute__((ext_vector_type(4))) float float4v;

__device__ __forceinline__ unsigned short f2bf(float f) {
    union { float f; unsigned int u; } c; c.f = f;
    unsigned int r = (c.u + 0x7FFFu + ((c.u >> 16) & 1u)) >> 16;  // RNE
    return (unsigned short)r;
}
__device__ __forceinline__ float bf2f(unsigned short u) {
    union { unsigned int u; float f; } c; c.u = ((unsigned int)u) << 16;
    return c.f;
}

// ---------------------------------------------------------------------------
// CSR build step 1: degree histogram, 4 edges/thread (ILP on the atomics).
// ---------------------------------------------------------------------------
__global__ __launch_bounds__(256) void count_kernel(
    const int* __restrict__ dst, int* __restrict__ deg, int E)
{
    int i = (blockIdx.x * 256 + threadIdx.x) * 4;
    if (i + 3 < E) {
        int4 d = *(const int4*)&dst[i];
        atomicAdd(&deg[d.x], 1);
        atomicAdd(&deg[d.y], 1);
        atomicAdd(&deg[d.z], 1);
        atomicAdd(&deg[d.w], 1);
    } else {
        for (int k = i; k < E; k++) atomicAdd(&deg[dst[k]], 1);
    }
}

// ---------------------------------------------------------------------------
// CSR build step 2a: per-block (1024-elem) partial sums of deg.
// ---------------------------------------------------------------------------
__global__ __launch_bounds__(256) void partial_kernel(
    const int* __restrict__ deg, int* __restrict__ part, int n)
{
    __shared__ int sm[256];
    const int base = blockIdx.x * 1024;
    const int t = threadIdx.x;
    int s = 0;
#pragma unroll
    for (int i = 0; i < 4; i++) {
        int idx = base + t + i * 256;
        if (idx < n) s += deg[idx];
    }
    sm[t] = s;
    __syncthreads();
    for (int off = 128; off > 0; off >>= 1) {
        if (t < off) sm[t] += sm[t + off];
        __syncthreads();
    }
    if (t == 0) part[blockIdx.x] = sm[0];
}

// ---------------------------------------------------------------------------
// CSR build step 2b: exclusive scan of the block partials (nb <= 256),
// writes rowptr[n] = total.
// ---------------------------------------------------------------------------
__global__ __launch_bounds__(256) void scanpart_kernel(
    int* __restrict__ part, int* __restrict__ rowptr, int nb, int n)
{
    __shared__ int sm[256];
    const int t = threadIdx.x;
    sm[t] = (t < nb) ? part[t] : 0;
    __syncthreads();
    if (t == 0) {
        int acc = 0;
        for (int i = 0; i < nb; i++) { int v = sm[i]; sm[i] = acc; acc += v; }
        rowptr[n] = acc;
    }
    __syncthreads();
    if (t < nb) part[t] = sm[t];
}

// ---------------------------------------------------------------------------
// CSR build step 2c: intra-block exclusive scan (4 elems/thread + LDS
// Hillis-Steele over thread sums), add block offset; write rowptr[i] and
// deg[i] = cursor start for the bucket pass.
// ---------------------------------------------------------------------------
__global__ __launch_bounds__(256) void apply_kernel(
    int* __restrict__ deg, const int* __restrict__ part,
    int* __restrict__ rowptr, int n)
{
    __shared__ int sm[256];
    const int base = blockIdx.x * 1024;
    const int t = threadIdx.x;
    const int i0 = base + t * 4;

    int4 d = {0, 0, 0, 0};
    if (i0 + 3 < n) {
        d = *(const int4*)&deg[i0];
    } else {
        if (i0 + 0 < n) d.x = deg[i0 + 0];
        if (i0 + 1 < n) d.y = deg[i0 + 1];
        if (i0 + 2 < n) d.z = deg[i0 + 2];
        if (i0 + 3 < n) d.w = deg[i0 + 3];
    }
    const int ts = d.x + d.y + d.z + d.w;
    sm[t] = ts;
    __syncthreads();
    for (int off = 1; off < 256; off <<= 1) {
        int u = (t >= off) ? sm[t - off] : 0;
        __syncthreads();
        sm[t] += u;
        __syncthreads();
    }
    int pref = part[blockIdx.x] + sm[t] - ts;  // exclusive prefix for i0

    int p0 = pref;
    int p1 = p0 + d.x;
    int p2 = p1 + d.y;
    int p3 = p2 + d.z;
    if (i0 + 0 < n) { rowptr[i0 + 0] = p0; deg[i0 + 0] = p0; }
    if (i0 + 1 < n) { rowptr[i0 + 1] = p1; deg[i0 + 1] = p1; }
    if (i0 + 2 < n) { rowptr[i0 + 2] = p2; deg[i0 + 2] = p2; }
    if (i0 + 3 < n) { rowptr[i0 + 3] = p3; deg[i0 + 3] = p3; }
}

// ---------------------------------------------------------------------------
// CSR build step 3: bucket src ids by dst, 4 edges/thread.
// ---------------------------------------------------------------------------
__global__ __launch_bounds__(256) void bucket_kernel(
    const int* __restrict__ src, const int* __restrict__ dst,
    int* __restrict__ pos, int* __restrict__ bsrc, int E)
{
    int i = (blockIdx.x * 256 + threadIdx.x) * 4;
    if (i + 3 < E) {
        int4 d = *(const int4*)&dst[i];
        int4 s = *(const int4*)&src[i];
        int p0 = atomicAdd(&pos[d.x], 1);
        int p1 = atomicAdd(&pos[d.y], 1);
        int p2 = atomicAdd(&pos[d.z], 1);
        int p3 = atomicAdd(&pos[d.w], 1);
        bsrc[p0] = s.x;
        bsrc[p1] = s.y;
        bsrc[p2] = s.z;
        bsrc[p3] = s.w;
    } else {
        for (int k = i; k < E; k++) {
            int p = atomicAdd(&pos[dst[k]], 1);
            bsrc[p] = src[k];
        }
    }
}

// ---------------------------------------------------------------------------
// Aggregation, fp32 source -> bf16 mean at row pitch `pitch`.
// One wave per row; lane owns 4 of 256 channels; 4 edges in flight.
// ---------------------------------------------------------------------------
__global__ __launch_bounds__(256) void agg_f32_kernel(
    const float* __restrict__ xsrc,     // [*, 256] fp32
    const int* __restrict__ rowptr,
    const int* __restrict__ bsrc,
    unsigned short* __restrict__ outp,  // bf16
    int pitch, int n)
{
    int row = blockIdx.x * 4 + (threadIdx.x >> 6);
    if (row >= n) return;
    const int lane = threadIdx.x & 63;
    const int beg = rowptr[row];
    const int end = rowptr[row + 1];

    float4 a0 = {0.f, 0.f, 0.f, 0.f};
    float4 a1 = {0.f, 0.f, 0.f, 0.f};
    float4 a2 = {0.f, 0.f, 0.f, 0.f};
    float4 a3 = {0.f, 0.f, 0.f, 0.f};
    int e = beg;
    for (; e + 3 < end; e += 4) {
        int s0 = bsrc[e + 0];
        int s1 = bsrc[e + 1];
        int s2 = bsrc[e + 2];
        int s3 = bsrc[e + 3];
        float4 v0 = ((const float4*)(xsrc + (size_t)s0 * 256))[lane];
        float4 v1 = ((const float4*)(xsrc + (size_t)s1 * 256))[lane];
        float4 v2 = ((const float4*)(xsrc + (size_t)s2 * 256))[lane];
        float4 v3 = ((const float4*)(xsrc + (size_t)s3 * 256))[lane];
        a0.x += v0.x; a0.y += v0.y; a0.z += v0.z; a0.w += v0.w;
        a1.x += v1.x; a1.y += v1.y; a1.z += v1.z; a1.w += v1.w;
        a2.x += v2.x; a2.y += v2.y; a2.z += v2.z; a2.w += v2.w;
        a3.x += v3.x; a3.y += v3.y; a3.z += v3.z; a3.w += v3.w;
    }
    for (; e < end; e++) {
        int s0 = bsrc[e];
        float4 v0 = ((const float4*)(xsrc + (size_t)s0 * 256))[lane];
        a0.x += v0.x; a0.y += v0.y; a0.z += v0.z; a0.w += v0.w;
    }
    float inv = 1.0f / fmaxf((float)(end - beg), 1.0f);
    ushort4 r;
    r.x = f2bf((a0.x + a1.x + a2.x + a3.x) * inv);
    r.y = f2bf((a0.y + a1.y + a2.y + a3.y) * inv);
    r.z = f2bf((a0.z + a1.z + a2.z + a3.z) * inv);
    r.w = f2bf((a0.w + a1.w + a2.w + a3.w) * inv);
    *(ushort4*)(outp + (size_t)row * pitch + lane * 4) = r;
}

// Aggregation, bf16 source (h) -> bf16 mean.
__global__ __launch_bounds__(256) void agg_bf16_kernel(
    const unsigned short* __restrict__ hsrc,  // [*, 256] bf16
    const int* __restrict__ rowptr,
    const int* __restrict__ bsrc,
    unsigned short* __restrict__ outp,
    int pitch, int n)
{
    int row = blockIdx.x * 4 + (threadIdx.x >> 6);
    if (row >= n) return;
    const int lane = threadIdx.x & 63;
    const int beg = rowptr[row];
    const int end = rowptr[row + 1];

    float4 a0 = {0.f, 0.f, 0.f, 0.f};
    float4 a1 = {0.f, 0.f, 0.f, 0.f};
    float4 a2 = {0.f, 0.f, 0.f, 0.f};
    float4 a3 = {0.f, 0.f, 0.f, 0.f};
    int e = beg;
    for (; e + 3 < end; e += 4) {
        int s0 = bsrc[e + 0];
        int s1 = bsrc[e + 1];
        int s2 = bsrc[e + 2];
        int s3 = bsrc[e + 3];
        ushort4 u0 = *(const ushort4*)(hsrc + (size_t)s0 * 256 + lane * 4);
        ushort4 u1 = *(const ushort4*)(hsrc + (size_t)s1 * 256 + lane * 4);
        ushort4 u2 = *(const ushort4*)(hsrc + (size_t)s2 * 256 + lane * 4);
        ushort4 u3 = *(const ushort4*)(hsrc + (size_t)s3 * 256 + lane * 4);
        a0.x += bf2f(u0.x); a0.y += bf2f(u0.y); a0.z += bf2f(u0.z); a0.w += bf2f(u0.w);
        a1.x += bf2f(u1.x); a1.y += bf2f(u1.y); a1.z += bf2f(u1.z); a1.w += bf2f(u1.w);
        a2.x += bf2f(u2.x); a2.y += bf2f(u2.y); a2.z += bf2f(u2.z); a2.w += bf2f(u2.w);
        a3.x += bf2f(u3.x); a3.y += bf2f(u3.y); a3.z += bf2f(u3.z); a3.w += bf2f(u3.w);
    }
    for (; e < end; e++) {
        int s0 = bsrc[e];
        ushort4 u0 = *(const ushort4*)(hsrc + (size_t)s0 * 256 + lane * 4);
        a0.x += bf2f(u0.x); a0.y += bf2f(u0.y); a0.z += bf2f(u0.z); a0.w += bf2f(u0.w);
    }
    float inv = 1.0f / fmaxf((float)(end - beg), 1.0f);
    ushort4 r;
    r.x = f2bf((a0.x + a1.x + a2.x + a3.x) * inv);
    r.y = f2bf((a0.y + a1.y + a2.y + a3.y) * inv);
    r.z = f2bf((a0.z + a1.z + a2.z + a3.z) * inv);
    r.w = f2bf((a0.w + a1.w + a2.w + a3.w) * inv);
    *(ushort4*)(outp + (size_t)row * pitch + lane * 4) = r;
}

// ---------------------------------------------------------------------------
// Pack seg1 (x_dst) and seg2 (0.25*attr[batch]) into abuf, fp32->bf16.
// ---------------------------------------------------------------------------
__global__ __launch_bounds__(256) void pack0_kernel(
    const float* __restrict__ x, const float* __restrict__ attr,
    const int* __restrict__ batch, unsigned short* __restrict__ abuf, int n)
{
    int row = blockIdx.x * 4 + (threadIdx.x >> 6);
    if (row >= n) return;
    const int lane = threadIdx.x & 63;
    float4 xv = ((const float4*)(x + (size_t)row * 256))[lane];
    int b = batch[row];
    float4 av = ((const float4*)(attr + (size_t)b * 256))[lane];
    unsigned short* dst = abuf + (size_t)row * 768;
    ushort4 r1; r1.x = f2bf(xv.x); r1.y = f2bf(xv.y); r1.z = f2bf(xv.z); r1.w = f2bf(xv.w);
    *(ushort4*)(dst + 256 + lane * 4) = r1;
    ushort4 r2; r2.x = f2bf(0.25f * av.x); r2.y = f2bf(0.25f * av.y);
    r2.z = f2bf(0.25f * av.z); r2.w = f2bf(0.25f * av.w);
    *(ushort4*)(dst + 512 + lane * 4) = r2;
}

__global__ __launch_bounds__(256) void pack1_kernel(
    const unsigned short* __restrict__ h, const float* __restrict__ attr,
    const int* __restrict__ batch, unsigned short* __restrict__ abuf, int n)
{
    int row = blockIdx.x * 4 + (threadIdx.x >> 6);
    if (row >= n) return;
    const int lane = threadIdx.x & 63;
    ushort4 hv = *(const ushort4*)(h + (size_t)row * 256 + lane * 4);
    int b = batch[row];
    float4 av = ((const float4*)(attr + (size_t)b * 256))[lane];
    unsigned short* dst = abuf + (size_t)row * 768;
    *(ushort4*)(dst + 256 + lane * 4) = hv;
    ushort4 r2; r2.x = f2bf(0.25f * av.x); r2.y = f2bf(0.25f * av.y);
    r2.z = f2bf(0.25f * av.z); r2.w = f2bf(0.25f * av.w);
    *(ushort4*)(dst + 512 + lane * 4) = r2;
}

// ---------------------------------------------------------------------------
// Weight transpose+cvt: Wt[n][k] bf16, k = [Wl | Wr | Wa]; bias = bl+0.25*ba.
// ---------------------------------------------------------------------------
__global__ __launch_bounds__(256) void wcvt_kernel(
    const float* __restrict__ Wl, const float* __restrict__ Wr,
    const float* __restrict__ Wa, const float* __restrict__ bl,
    const float* __restrict__ ba, unsigned short* __restrict__ Wt,
    float* __restrict__ bias, int N)
{
    int k = blockIdx.x * 256 + threadIdx.x;  // 0..767
    int n = blockIdx.y;
    const float* W; int kk;
    if (k < 256)      { W = Wl; kk = k; }
    else if (k < 512) { W = Wr; kk = k - 256; }
    else              { W = Wa; kk = k - 512; }
    Wt[(size_t)n * 768 + k] = f2bf(W[(size_t)kk * N + n]);
    if (k == 0) bias[n] = bl[n] + 0.25f * ba[n];
}

// ---------------------------------------------------------------------------
// bf16 MFMA GEMM: C = relu(A @ Wt^T + bias). (unchanged from round 3)
// ---------------------------------------------------------------------------
template<bool OUT_BF16>
__global__ __launch_bounds__(256) void gemm_mfma_kernel(
    const unsigned short* __restrict__ A,   // [Mpad][768]
    const unsigned short* __restrict__ Wt,  // [N][768]
    const float* __restrict__ bias,         // [N]
    void* __restrict__ Cout, int M, int ldc)
{
    __shared__ unsigned short As[128 * 72];
    __shared__ unsigned short Bs[128 * 72];
    const int tid  = threadIdx.x;
    const int lane = tid & 63;
    const int wave = tid >> 6;
    const int lm   = lane & 15;
    const int quad = lane >> 4;
    const int wm   = (wave & 1) * 64;
    const int wn   = (wave >> 1) * 64;
    const int m0   = blockIdx.x * 128;
    const int n0   = blockIdx.y * 128;

    float4v acc[4][4];
#pragma unroll
    for (int i = 0; i < 4; i++)
#pragma unroll
        for (int j = 0; j < 4; j++)
            acc[i][j] = (float4v){0.f, 0.f, 0.f, 0.f};

    for (int kt = 0; kt < 768; kt += 64) {
#pragma unroll
        for (int i = 0; i < 4; i++) {
            int c = i * 256 + tid;
            int row = c >> 3;
            int col = (c & 7) * 8;
            *(uint4*)&As[row * 72 + col] =
                *(const uint4*)&A[(size_t)(m0 + row) * 768 + kt + col];
            *(uint4*)&Bs[row * 72 + col] =
                *(const uint4*)&Wt[(size_t)(n0 + row) * 768 + kt + col];
        }
        __syncthreads();

#pragma unroll
        for (int h = 0; h < 2; h++) {
            short8 a[4], b[4];
#pragma unroll
            for (int i = 0; i < 4; i++)
                a[i] = *(const short8*)&As[(wm + i * 16 + lm) * 72 + h * 32 + quad * 8];
#pragma unroll
            for (int j = 0; j < 4; j++)
                b[j] = *(const short8*)&Bs[(wn + j * 16 + lm) * 72 + h * 32 + quad * 8];
#pragma unroll
            for (int i = 0; i < 4; i++)
#pragma unroll
                for (int j = 0; j < 4; j++)
                    acc[i][j] = __builtin_amdgcn_mfma_f32_16x16x32_bf16(
                        a[i], b[j], acc[i][j], 0, 0, 0);
        }
        __syncthreads();
    }

    float bcol[4];
#pragma unroll
    for (int j = 0; j < 4; j++) bcol[j] = bias[n0 + wn + j * 16 + lm];

#pragma unroll
    for (int i = 0; i < 4; i++) {
        int rbase = m0 + wm + i * 16 + quad * 4;
#pragma unroll
        for (int j = 0; j < 4; j++) {
            int col = n0 + wn + j * 16 + lm;
#pragma unroll
            for (int r = 0; r < 4; r++) {
                int row = rbase + r;
                if (row < M) {
                    float v = fmaxf(acc[i][j][r] + bcol[j], 0.f);
                    if (OUT_BF16)
                        ((unsigned short*)Cout)[(size_t)row * ldc + col] = f2bf(v);
                    else
                        ((float*)Cout)[(size_t)row * ldc + col] = v;
                }
            }
        }
    }
}

// ---------------------------------------------------------------------------
// Launch
// ---------------------------------------------------------------------------
extern "C" void kernel_launch(void* const* d_in, const int* in_sizes, int n_in,
                              void* d_out, int out_size, void* d_ws, size_t ws_size,
                              hipStream_t stream) {
    const float* x     = (const float*)d_in[0];
    const float* attr  = (const float*)d_in[1];
    const int* src0    = (const int*)d_in[2];
    const int* dst0    = (const int*)d_in[3];
    const int* src1    = (const int*)d_in[4];
    const int* dst1    = (const int*)d_in[5];
    const int* batch0  = (const int*)d_in[6];
    const int* batch1  = (const int*)d_in[7];
    const float* W_l0  = (const float*)d_in[8];
    const float* b_l0  = (const float*)d_in[9];
    const float* W_r0  = (const float*)d_in[10];
    const float* W_l1  = (const float*)d_in[11];
    const float* b_l1  = (const float*)d_in[12];
    const float* W_r1  = (const float*)d_in[13];
    const float* W_a0  = (const float*)d_in[14];
    const float* b_a0  = (const float*)d_in[15];
    const float* W_a1  = (const float*)d_in[16];
    const float* b_a1  = (const float*)d_in[17];
    float* out = (float*)d_out;

    const int E0 = in_sizes[2];   // 1600000
    const int E1 = in_sizes[4];   // 320000
    const int N1 = in_sizes[6];   // 50000
    const int N2 = in_sizes[7];   // 10000
    const int MP0 = 50048;        // 391*128
    const int MP1 = 10112;        // 79*128
    const int NB0 = (N1 + 1023) / 1024;  // 49
    const int NB1 = (N2 + 1023) / 1024;  // 10

    // workspace layout (~110 MB)
    char* p = (char*)d_ws;
    unsigned short* abuf = (unsigned short*)p;      // [50048][768] bf16 (76.9MB)
    p += (size_t)MP0 * 768 * 2;
    unsigned short* h = (unsigned short*)p;         // [50048][256] bf16 (25.6MB)
    p += (size_t)MP0 * 256 * 2;
    unsigned short* Wt0 = (unsigned short*)p; p += (size_t)256 * 768 * 2;
    unsigned short* Wt1 = (unsigned short*)p; p += (size_t)128 * 768 * 2;
    float* bias0 = (float*)p; p += 256 * 4;
    float* bias1 = (float*)p; p += 128 * 4;
    int* bsrc0   = (int*)p;                         // E0 ints (6.4MB)
    int* rowptr0 = bsrc0 + E0;                      // N1+1
    int* deg0    = rowptr0 + N1 + 1;                // N1
    int* part0   = deg0 + N1;                       // 256
    // layer-1 CSR aliases bsrc0's region (bsrc0 dead after agg_f32)
    int* bsrc1   = bsrc0;                           // E1
    int* rowptr1 = bsrc1 + E1;                      // N2+1
    int* deg1    = rowptr1 + N2 + 1;                // N2
    int* part1   = deg1 + N2;                       // 256

    // ---- layer 0 ----
    hipMemsetAsync(deg0, 0, (size_t)N1 * sizeof(int), stream);
    count_kernel<<<(E0 / 4 + 255) / 256, 256, 0, stream>>>(dst0, deg0, E0);
    partial_kernel<<<NB0, 256, 0, stream>>>(deg0, part0, N1);
    scanpart_kernel<<<1, 256, 0, stream>>>(part0, rowptr0, NB0, N1);
    apply_kernel<<<NB0, 256, 0, stream>>>(deg0, part0, rowptr0, N1);
    bucket_kernel<<<(E0 / 4 + 255) / 256, 256, 0, stream>>>(src0, dst0, deg0, bsrc0, E0);
    agg_f32_kernel<<<(N1 + 3) / 4, 256, 0, stream>>>(x, rowptr0, bsrc0, abuf, 768, N1);
    pack0_kernel<<<(N1 + 3) / 4, 256, 0, stream>>>(x, attr, batch0, abuf, N1);
    wcvt_kernel<<<dim3(3, 256), 256, 0, stream>>>(W_l0, W_r0, W_a0, b_l0, b_a0,
                                                  Wt0, bias0, 256);
    gemm_mfma_kernel<true><<<dim3(MP0 / 128, 2), 256, 0, stream>>>(
        abuf, Wt0, bias0, h, MP0, 256);

    // ---- layer 1 ----
    hipMemsetAsync(deg1, 0, (size_t)N2 * sizeof(int), stream);
    count_kernel<<<(E1 / 4 + 255) / 256, 256, 0, stream>>>(dst1, deg1, E1);
    partial_kernel<<<NB1, 256, 0, stream>>>(deg1, part1, N2);
    scanpart_kernel<<<1, 256, 0, stream>>>(part1, rowptr1, NB1, N2);
    apply_kernel<<<NB1, 256, 0, stream>>>(deg1, part1, rowptr1, N2);
    bucket_kernel<<<(E1 / 4 + 255) / 256, 256, 0, stream>>>(src1, dst1, deg1, bsrc1, E1);
    agg_bf16_kernel<<<(N2 + 3) / 4, 256, 0, stream>>>(h, rowptr1, bsrc1, abuf, 768, N2);
    pack1_kernel<<<(N2 + 3) / 4, 256, 0, stream>>>(h, attr, batch1, abuf, N2);
    wcvt_kernel<<<dim3(3, 128), 256, 0, stream>>>(W_l1, W_r1, W_a1, b_l1, b_a1,
                                                  Wt1, bias1, 128);
    gemm_mfma_kernel<false><<<dim3(MP1 / 128, 1), 256, 0, stream>>>(
        abuf, Wt1, bias1, out, N2, 128);
}

// Round 5
// 910.840 us; speedup vs baseline: 8.6688x; 1.0689x over previous
//
#include <hip/hip_runtime.h>

// Problem constants (fixed by the reference):
//   N0=200000, N1=50000, N2=10000, E0=1600000, E1=320000
//   IN_CH=256, HID=256, OUT=128,  K = 3*256 = 768
//
// Round 5: the layer-0 aggregation is bytes-bound on random 1KB row gathers
// (round-4 ILP was neutral: 253us, HBM 41%, VALU 11%). Convert x to bf16
// once (~55us streaming) and gather 512B bf16 rows instead: halves gather
// traffic and makes x L3-resident (100MB < 256MB). Falls back to the
// round-4 fp32 path if ws_size can't hold the +100MB bf16 copy.

typedef __attribute__((ext_vector_type(8))) short short8;
typedef __attribute__((ext_vector_type(4))) float float4v;

__device__ __forceinline__ unsigned short f2bf(float f) {
    union { float f; unsigned int u; } c; c.f = f;
    unsigned int r = (c.u + 0x7FFFu + ((c.u >> 16) & 1u)) >> 16;  // RNE
    return (unsigned short)r;
}
__device__ __forceinline__ float bf2f(unsigned short u) {
    union { unsigned int u; float f; } c; c.u = ((unsigned int)u) << 16;
    return c.f;
}

// ---------------------------------------------------------------------------
// fp32 -> bf16 streaming convert (4 elems/thread).
// ---------------------------------------------------------------------------
__global__ __launch_bounds__(256) void xcvt_kernel(
    const float* __restrict__ x, unsigned short* __restrict__ xb, int n4)
{
    int i = blockIdx.x * 256 + threadIdx.x;
    if (i < n4) {
        float4 v = ((const float4*)x)[i];
        ushort4 r;
        r.x = f2bf(v.x); r.y = f2bf(v.y); r.z = f2bf(v.z); r.w = f2bf(v.w);
        ((ushort4*)xb)[i] = r;
    }
}

// ---------------------------------------------------------------------------
// CSR build step 1: degree histogram, 4 edges/thread.
// ---------------------------------------------------------------------------
__global__ __launch_bounds__(256) void count_kernel(
    const int* __restrict__ dst, int* __restrict__ deg, int E)
{
    int i = (blockIdx.x * 256 + threadIdx.x) * 4;
    if (i + 3 < E) {
        int4 d = *(const int4*)&dst[i];
        atomicAdd(&deg[d.x], 1);
        atomicAdd(&deg[d.y], 1);
        atomicAdd(&deg[d.z], 1);
        atomicAdd(&deg[d.w], 1);
    } else {
        for (int k = i; k < E; k++) atomicAdd(&deg[dst[k]], 1);
    }
}

// ---------------------------------------------------------------------------
// CSR build step 2a: per-block (1024-elem) partial sums of deg.
// ---------------------------------------------------------------------------
__global__ __launch_bounds__(256) void partial_kernel(
    const int* __restrict__ deg, int* __restrict__ part, int n)
{
    __shared__ int sm[256];
    const int base = blockIdx.x * 1024;
    const int t = threadIdx.x;
    int s = 0;
#pragma unroll
    for (int i = 0; i < 4; i++) {
        int idx = base + t + i * 256;
        if (idx < n) s += deg[idx];
    }
    sm[t] = s;
    __syncthreads();
    for (int off = 128; off > 0; off >>= 1) {
        if (t < off) sm[t] += sm[t + off];
        __syncthreads();
    }
    if (t == 0) part[blockIdx.x] = sm[0];
}

// ---------------------------------------------------------------------------
// CSR build step 2b: exclusive scan of block partials (nb <= 256).
// ---------------------------------------------------------------------------
__global__ __launch_bounds__(256) void scanpart_kernel(
    int* __restrict__ part, int* __restrict__ rowptr, int nb, int n)
{
    __shared__ int sm[256];
    const int t = threadIdx.x;
    sm[t] = (t < nb) ? part[t] : 0;
    __syncthreads();
    if (t == 0) {
        int acc = 0;
        for (int i = 0; i < nb; i++) { int v = sm[i]; sm[i] = acc; acc += v; }
        rowptr[n] = acc;
    }
    __syncthreads();
    if (t < nb) part[t] = sm[t];
}

// ---------------------------------------------------------------------------
// CSR build step 2c: intra-block exclusive scan; rowptr + cursor init.
// ---------------------------------------------------------------------------
__global__ __launch_bounds__(256) void apply_kernel(
    int* __restrict__ deg, const int* __restrict__ part,
    int* __restrict__ rowptr, int n)
{
    __shared__ int sm[256];
    const int base = blockIdx.x * 1024;
    const int t = threadIdx.x;
    const int i0 = base + t * 4;

    int4 d = {0, 0, 0, 0};
    if (i0 + 3 < n) {
        d = *(const int4*)&deg[i0];
    } else {
        if (i0 + 0 < n) d.x = deg[i0 + 0];
        if (i0 + 1 < n) d.y = deg[i0 + 1];
        if (i0 + 2 < n) d.z = deg[i0 + 2];
        if (i0 + 3 < n) d.w = deg[i0 + 3];
    }
    const int ts = d.x + d.y + d.z + d.w;
    sm[t] = ts;
    __syncthreads();
    for (int off = 1; off < 256; off <<= 1) {
        int u = (t >= off) ? sm[t - off] : 0;
        __syncthreads();
        sm[t] += u;
        __syncthreads();
    }
    int pref = part[blockIdx.x] + sm[t] - ts;

    int p0 = pref;
    int p1 = p0 + d.x;
    int p2 = p1 + d.y;
    int p3 = p2 + d.z;
    if (i0 + 0 < n) { rowptr[i0 + 0] = p0; deg[i0 + 0] = p0; }
    if (i0 + 1 < n) { rowptr[i0 + 1] = p1; deg[i0 + 1] = p1; }
    if (i0 + 2 < n) { rowptr[i0 + 2] = p2; deg[i0 + 2] = p2; }
    if (i0 + 3 < n) { rowptr[i0 + 3] = p3; deg[i0 + 3] = p3; }
}

// ---------------------------------------------------------------------------
// CSR build step 3: bucket src ids by dst, 4 edges/thread.
// ---------------------------------------------------------------------------
__global__ __launch_bounds__(256) void bucket_kernel(
    const int* __restrict__ src, const int* __restrict__ dst,
    int* __restrict__ pos, int* __restrict__ bsrc, int E)
{
    int i = (blockIdx.x * 256 + threadIdx.x) * 4;
    if (i + 3 < E) {
        int4 d = *(const int4*)&dst[i];
        int4 s = *(const int4*)&src[i];
        int p0 = atomicAdd(&pos[d.x], 1);
        int p1 = atomicAdd(&pos[d.y], 1);
        int p2 = atomicAdd(&pos[d.z], 1);
        int p3 = atomicAdd(&pos[d.w], 1);
        bsrc[p0] = s.x;
        bsrc[p1] = s.y;
        bsrc[p2] = s.z;
        bsrc[p3] = s.w;
    } else {
        for (int k = i; k < E; k++) {
            int p = atomicAdd(&pos[dst[k]], 1);
            bsrc[p] = src[k];
        }
    }
}

// ---------------------------------------------------------------------------
// Aggregation, fp32 source -> bf16 mean (fallback path only).
// ---------------------------------------------------------------------------
__global__ __launch_bounds__(256) void agg_f32_kernel(
    const float* __restrict__ xsrc,
    const int* __restrict__ rowptr,
    const int* __restrict__ bsrc,
    unsigned short* __restrict__ outp,
    int pitch, int n)
{
    int row = blockIdx.x * 4 + (threadIdx.x >> 6);
    if (row >= n) return;
    const int lane = threadIdx.x & 63;
    const int beg = rowptr[row];
    const int end = rowptr[row + 1];

    float4 a0 = {0.f, 0.f, 0.f, 0.f};
    float4 a1 = {0.f, 0.f, 0.f, 0.f};
    float4 a2 = {0.f, 0.f, 0.f, 0.f};
    float4 a3 = {0.f, 0.f, 0.f, 0.f};
    int e = beg;
    for (; e + 3 < end; e += 4) {
        int s0 = bsrc[e + 0];
        int s1 = bsrc[e + 1];
        int s2 = bsrc[e + 2];
        int s3 = bsrc[e + 3];
        float4 v0 = ((const float4*)(xsrc + (size_t)s0 * 256))[lane];
        float4 v1 = ((const float4*)(xsrc + (size_t)s1 * 256))[lane];
        float4 v2 = ((const float4*)(xsrc + (size_t)s2 * 256))[lane];
        float4 v3 = ((const float4*)(xsrc + (size_t)s3 * 256))[lane];
        a0.x += v0.x; a0.y += v0.y; a0.z += v0.z; a0.w += v0.w;
        a1.x += v1.x; a1.y += v1.y; a1.z += v1.z; a1.w += v1.w;
        a2.x += v2.x; a2.y += v2.y; a2.z += v2.z; a2.w += v2.w;
        a3.x += v3.x; a3.y += v3.y; a3.z += v3.z; a3.w += v3.w;
    }
    for (; e < end; e++) {
        int s0 = bsrc[e];
        float4 v0 = ((const float4*)(xsrc + (size_t)s0 * 256))[lane];
        a0.x += v0.x; a0.y += v0.y; a0.z += v0.z; a0.w += v0.w;
    }
    float inv = 1.0f / fmaxf((float)(end - beg), 1.0f);
    ushort4 r;
    r.x = f2bf((a0.x + a1.x + a2.x + a3.x) * inv);
    r.y = f2bf((a0.y + a1.y + a2.y + a3.y) * inv);
    r.z = f2bf((a0.z + a1.z + a2.z + a3.z) * inv);
    r.w = f2bf((a0.w + a1.w + a2.w + a3.w) * inv);
    *(ushort4*)(outp + (size_t)row * pitch + lane * 4) = r;
}

// ---------------------------------------------------------------------------
// Aggregation, bf16 source -> bf16 mean. One wave per row, lane owns 4
// channels (8B loads -> 512B per row access), 4 edges in flight.
// ---------------------------------------------------------------------------
__global__ __launch_bounds__(256) void agg_bf16_kernel(
    const unsigned short* __restrict__ hsrc,  // [*, 256] bf16
    const int* __restrict__ rowptr,
    const int* __restrict__ bsrc,
    unsigned short* __restrict__ outp,
    int pitch, int n)
{
    int row = blockIdx.x * 4 + (threadIdx.x >> 6);
    if (row >= n) return;
    const int lane = threadIdx.x & 63;
    const int beg = rowptr[row];
    const int end = rowptr[row + 1];

    float4 a0 = {0.f, 0.f, 0.f, 0.f};
    float4 a1 = {0.f, 0.f, 0.f, 0.f};
    float4 a2 = {0.f, 0.f, 0.f, 0.f};
    float4 a3 = {0.f, 0.f, 0.f, 0.f};
    int e = beg;
    for (; e + 3 < end; e += 4) {
        int s0 = bsrc[e + 0];
        int s1 = bsrc[e + 1];
        int s2 = bsrc[e + 2];
        int s3 = bsrc[e + 3];
        ushort4 u0 = *(const ushort4*)(hsrc + (size_t)s0 * 256 + lane * 4);
        ushort4 u1 = *(const ushort4*)(hsrc + (size_t)s1 * 256 + lane * 4);
        ushort4 u2 = *(const ushort4*)(hsrc + (size_t)s2 * 256 + lane * 4);
        ushort4 u3 = *(const ushort4*)(hsrc + (size_t)s3 * 256 + lane * 4);
        a0.x += bf2f(u0.x); a0.y += bf2f(u0.y); a0.z += bf2f(u0.z); a0.w += bf2f(u0.w);
        a1.x += bf2f(u1.x); a1.y += bf2f(u1.y); a1.z += bf2f(u1.z); a1.w += bf2f(u1.w);
        a2.x += bf2f(u2.x); a2.y += bf2f(u2.y); a2.z += bf2f(u2.z); a2.w += bf2f(u2.w);
        a3.x += bf2f(u3.x); a3.y += bf2f(u3.y); a3.z += bf2f(u3.z); a3.w += bf2f(u3.w);
    }
    for (; e < end; e++) {
        int s0 = bsrc[e];
        ushort4 u0 = *(const ushort4*)(hsrc + (size_t)s0 * 256 + lane * 4);
        a0.x += bf2f(u0.x); a0.y += bf2f(u0.y); a0.z += bf2f(u0.z); a0.w += bf2f(u0.w);
    }
    float inv = 1.0f / fmaxf((float)(end - beg), 1.0f);
    ushort4 r;
    r.x = f2bf((a0.x + a1.x + a2.x + a3.x) * inv);
    r.y = f2bf((a0.y + a1.y + a2.y + a3.y) * inv);
    r.z = f2bf((a0.z + a1.z + a2.z + a3.z) * inv);
    r.w = f2bf((a0.w + a1.w + a2.w + a3.w) * inv);
    *(ushort4*)(outp + (size_t)row * pitch + lane * 4) = r;
}

// ---------------------------------------------------------------------------
// Pack seg1 (x_dst) + seg2 (0.25*attr[batch]). fp32-x variant (fallback).
// ---------------------------------------------------------------------------
__global__ __launch_bounds__(256) void pack0_kernel(
    const float* __restrict__ x, const float* __restrict__ attr,
    const int* __restrict__ batch, unsigned short* __restrict__ abuf, int n)
{
    int row = blockIdx.x * 4 + (threadIdx.x >> 6);
    if (row >= n) return;
    const int lane = threadIdx.x & 63;
    float4 xv = ((const float4*)(x + (size_t)row * 256))[lane];
    int b = batch[row];
    float4 av = ((const float4*)(attr + (size_t)b * 256))[lane];
    unsigned short* dst = abuf + (size_t)row * 768;
    ushort4 r1; r1.x = f2bf(xv.x); r1.y = f2bf(xv.y); r1.z = f2bf(xv.z); r1.w = f2bf(xv.w);
    *(ushort4*)(dst + 256 + lane * 4) = r1;
    ushort4 r2; r2.x = f2bf(0.25f * av.x); r2.y = f2bf(0.25f * av.y);
    r2.z = f2bf(0.25f * av.z); r2.w = f2bf(0.25f * av.w);
    *(ushort4*)(dst + 512 + lane * 4) = r2;
}

// bf16-x variant (fast path): seg1 is a straight bf16 copy.
__global__ __launch_bounds__(256) void pack0b_kernel(
    const unsigned short* __restrict__ xb, const float* __restrict__ attr,
    const int* __restrict__ batch, unsigned short* __restrict__ abuf, int n)
{
    int row = blockIdx.x * 4 + (threadIdx.x >> 6);
    if (row >= n) return;
    const int lane = threadIdx.x & 63;
    ushort4 xv = *(const ushort4*)(xb + (size_t)row * 256 + lane * 4);
    int b = batch[row];
    float4 av = ((const float4*)(attr + (size_t)b * 256))[lane];
    unsigned short* dst = abuf + (size_t)row * 768;
    *(ushort4*)(dst + 256 + lane * 4) = xv;
    ushort4 r2; r2.x = f2bf(0.25f * av.x); r2.y = f2bf(0.25f * av.y);
    r2.z = f2bf(0.25f * av.z); r2.w = f2bf(0.25f * av.w);
    *(ushort4*)(dst + 512 + lane * 4) = r2;
}

// seg1 from bf16 h, seg2 from fp32 attr gather (layer 1).
__global__ __launch_bounds__(256) void pack1_kernel(
    const unsigned short* __restrict__ h, const float* __restrict__ attr,
    const int* __restrict__ batch, unsigned short* __restrict__ abuf, int n)
{
    int row = blockIdx.x * 4 + (threadIdx.x >> 6);
    if (row >= n) return;
    const int lane = threadIdx.x & 63;
    ushort4 hv = *(const ushort4*)(h + (size_t)row * 256 + lane * 4);
    int b = batch[row];
    float4 av = ((const float4*)(attr + (size_t)b * 256))[lane];
    unsigned short* dst = abuf + (size_t)row * 768;
    *(ushort4*)(dst + 256 + lane * 4) = hv;
    ushort4 r2; r2.x = f2bf(0.25f * av.x); r2.y = f2bf(0.25f * av.y);
    r2.z = f2bf(0.25f * av.z); r2.w = f2bf(0.25f * av.w);
    *(ushort4*)(dst + 512 + lane * 4) = r2;
}

// ---------------------------------------------------------------------------
// Weight transpose+cvt: Wt[n][k] bf16, k = [Wl | Wr | Wa]; bias = bl+0.25*ba.
// ---------------------------------------------------------------------------
__global__ __launch_bounds__(256) void wcvt_kernel(
    const float* __restrict__ Wl, const float* __restrict__ Wr,
    const float* __restrict__ Wa, const float* __restrict__ bl,
    const float* __restrict__ ba, unsigned short* __restrict__ Wt,
    float* __restrict__ bias, int N)
{
    int k = blockIdx.x * 256 + threadIdx.x;  // 0..767
    int n = blockIdx.y;
    const float* W; int kk;
    if (k < 256)      { W = Wl; kk = k; }
    else if (k < 512) { W = Wr; kk = k - 256; }
    else              { W = Wa; kk = k - 512; }
    Wt[(size_t)n * 768 + k] = f2bf(W[(size_t)kk * N + n]);
    if (k == 0) bias[n] = bl[n] + 0.25f * ba[n];
}

// ---------------------------------------------------------------------------
// bf16 MFMA GEMM: C = relu(A @ Wt^T + bias). (unchanged)
// ---------------------------------------------------------------------------
template<bool OUT_BF16>
__global__ __launch_bounds__(256) void gemm_mfma_kernel(
    const unsigned short* __restrict__ A,   // [Mpad][768]
    const unsigned short* __restrict__ Wt,  // [N][768]
    const float* __restrict__ bias,         // [N]
    void* __restrict__ Cout, int M, int ldc)
{
    __shared__ unsigned short As[128 * 72];
    __shared__ unsigned short Bs[128 * 72];
    const int tid  = threadIdx.x;
    const int lane = tid & 63;
    const int wave = tid >> 6;
    const int lm   = lane & 15;
    const int quad = lane >> 4;
    const int wm   = (wave & 1) * 64;
    const int wn   = (wave >> 1) * 64;
    const int m0   = blockIdx.x * 128;
    const int n0   = blockIdx.y * 128;

    float4v acc[4][4];
#pragma unroll
    for (int i = 0; i < 4; i++)
#pragma unroll
        for (int j = 0; j < 4; j++)
            acc[i][j] = (float4v){0.f, 0.f, 0.f, 0.f};

    for (int kt = 0; kt < 768; kt += 64) {
#pragma unroll
        for (int i = 0; i < 4; i++) {
            int c = i * 256 + tid;
            int row = c >> 3;
            int col = (c & 7) * 8;
            *(uint4*)&As[row * 72 + col] =
                *(const uint4*)&A[(size_t)(m0 + row) * 768 + kt + col];
            *(uint4*)&Bs[row * 72 + col] =
                *(const uint4*)&Wt[(size_t)(n0 + row) * 768 + kt + col];
        }
        __syncthreads();

#pragma unroll
        for (int h = 0; h < 2; h++) {
            short8 a[4], b[4];
#pragma unroll
            for (int i = 0; i < 4; i++)
                a[i] = *(const short8*)&As[(wm + i * 16 + lm) * 72 + h * 32 + quad * 8];
#pragma unroll
            for (int j = 0; j < 4; j++)
                b[j] = *(const short8*)&Bs[(wn + j * 16 + lm) * 72 + h * 32 + quad * 8];
#pragma unroll
            for (int i = 0; i < 4; i++)
#pragma unroll
                for (int j = 0; j < 4; j++)
                    acc[i][j] = __builtin_amdgcn_mfma_f32_16x16x32_bf16(
                        a[i], b[j], acc[i][j], 0, 0, 0);
        }
        __syncthreads();
    }

    float bcol[4];
#pragma unroll
    for (int j = 0; j < 4; j++) bcol[j] = bias[n0 + wn + j * 16 + lm];

#pragma unroll
    for (int i = 0; i < 4; i++) {
        int rbase = m0 + wm + i * 16 + quad * 4;
#pragma unroll
        for (int j = 0; j < 4; j++) {
            int col = n0 + wn + j * 16 + lm;
#pragma unroll
            for (int r = 0; r < 4; r++) {
                int row = rbase + r;
                if (row < M) {
                    float v = fmaxf(acc[i][j][r] + bcol[j], 0.f);
                    if (OUT_BF16)
                        ((unsigned short*)Cout)[(size_t)row * ldc + col] = f2bf(v);
                    else
                        ((float*)Cout)[(size_t)row * ldc + col] = v;
                }
            }
        }
    }
}

// ---------------------------------------------------------------------------
// Launch
// ---------------------------------------------------------------------------
extern "C" void kernel_launch(void* const* d_in, const int* in_sizes, int n_in,
                              void* d_out, int out_size, void* d_ws, size_t ws_size,
                              hipStream_t stream) {
    const float* x     = (const float*)d_in[0];
    const float* attr  = (const float*)d_in[1];
    const int* src0    = (const int*)d_in[2];
    const int* dst0    = (const int*)d_in[3];
    const int* src1    = (const int*)d_in[4];
    const int* dst1    = (const int*)d_in[5];
    const int* batch0  = (const int*)d_in[6];
    const int* batch1  = (const int*)d_in[7];
    const float* W_l0  = (const float*)d_in[8];
    const float* b_l0  = (const float*)d_in[9];
    const float* W_r0  = (const float*)d_in[10];
    const float* W_l1  = (const float*)d_in[11];
    const float* b_l1  = (const float*)d_in[12];
    const float* W_r1  = (const float*)d_in[13];
    const float* W_a0  = (const float*)d_in[14];
    const float* b_a0  = (const float*)d_in[15];
    const float* W_a1  = (const float*)d_in[16];
    const float* b_a1  = (const float*)d_in[17];
    float* out = (float*)d_out;

    const int N0 = in_sizes[0] / 256;  // 200000
    const int E0 = in_sizes[2];        // 1600000
    const int E1 = in_sizes[4];        // 320000
    const int N1 = in_sizes[6];        // 50000
    const int N2 = in_sizes[7];        // 10000
    const int MP0 = 50048;             // 391*128
    const int MP1 = 10112;             // 79*128
    const int NB0 = (N1 + 1023) / 1024;
    const int NB1 = (N2 + 1023) / 1024;

    const size_t abuf_b = (size_t)MP0 * 768 * 2;     // 76.87 MB
    const size_t xb_b   = (size_t)N0 * 256 * 2;      // 102.4 MB (fast path)
    const size_t h_b    = (size_t)MP0 * 256 * 2;     // 25.6 MB
    const size_t wt_b   = (size_t)256 * 768 * 2 + (size_t)128 * 768 * 2 + 1024 + 512;
    const size_t csr_b  = ((size_t)E0 + (N1 + 1) + N1 + 256) * 4;
    const bool fast = ws_size >= abuf_b + xb_b + wt_b + csr_b;

    char* p = (char*)d_ws;
    unsigned short* abuf = (unsigned short*)p;  p += abuf_b;
    unsigned short* xb;       // bf16 copy of x (fast path only)
    unsigned short* h;        // bf16 hidden layer; aliases xb (xb dead by gemm0)
    if (fast) { xb = (unsigned short*)p; h = xb; p += xb_b; }
    else      { xb = nullptr; h = (unsigned short*)p; p += h_b; }
    unsigned short* Wt0 = (unsigned short*)p; p += (size_t)256 * 768 * 2;
    unsigned short* Wt1 = (unsigned short*)p; p += (size_t)128 * 768 * 2;
    float* bias0 = (float*)p; p += 1024;
    float* bias1 = (float*)p; p += 512;
    int* bsrc0   = (int*)p;
    int* rowptr0 = bsrc0 + E0;
    int* deg0    = rowptr0 + N1 + 1;
    int* part0   = deg0 + N1;
    int* bsrc1   = bsrc0;                 // layer-1 CSR aliases layer-0's
    int* rowptr1 = bsrc1 + E1;
    int* deg1    = rowptr1 + N2 + 1;
    int* part1   = deg1 + N2;

    // ---- layer 0 ----
    hipMemsetAsync(deg0, 0, (size_t)N1 * sizeof(int), stream);
    if (fast)
        xcvt_kernel<<<(N0 * 256 / 4 + 255) / 256, 256, 0, stream>>>(x, xb, N0 * 256 / 4);
    count_kernel<<<(E0 / 4 + 255) / 256, 256, 0, stream>>>(dst0, deg0, E0);
    partial_kernel<<<NB0, 256, 0, stream>>>(deg0, part0, N1);
    scanpart_kernel<<<1, 256, 0, stream>>>(part0, rowptr0, NB0, N1);
    apply_kernel<<<NB0, 256, 0, stream>>>(deg0, part0, rowptr0, N1);
    bucket_kernel<<<(E0 / 4 + 255) / 256, 256, 0, stream>>>(src0, dst0, deg0, bsrc0, E0);
    if (fast) {
        agg_bf16_kernel<<<(N1 + 3) / 4, 256, 0, stream>>>(xb, rowptr0, bsrc0, abuf, 768, N1);
        pack0b_kernel<<<(N1 + 3) / 4, 256, 0, stream>>>(xb, attr, batch0, abuf, N1);
    } else {
        agg_f32_kernel<<<(N1 + 3) / 4, 256, 0, stream>>>(x, rowptr0, bsrc0, abuf, 768, N1);
        pack0_kernel<<<(N1 + 3) / 4, 256, 0, stream>>>(x, attr, batch0, abuf, N1);
    }
    wcvt_kernel<<<dim3(3, 256), 256, 0, stream>>>(W_l0, W_r0, W_a0, b_l0, b_a0,
                                                  Wt0, bias0, 256);
    // gemm0 writes h; on the fast path this overwrites xb, which is dead here.
    gemm_mfma_kernel<true><<<dim3(MP0 / 128, 2), 256, 0, stream>>>(
        abuf, Wt0, bias0, h, MP0, 256);

    // ---- layer 1 ----
    hipMemsetAsync(deg1, 0, (size_t)N2 * sizeof(int), stream);
    count_kernel<<<(E1 / 4 + 255) / 256, 256, 0, stream>>>(dst1, deg1, E1);
    partial_kernel<<<NB1, 256, 0, stream>>>(deg1, part1, N2);
    scanpart_kernel<<<1, 256, 0, stream>>>(part1, rowptr1, NB1, N2);
    apply_kernel<<<NB1, 256, 0, stream>>>(deg1, part1, rowptr1, N2);
    bucket_kernel<<<(E1 / 4 + 255) / 256, 256, 0, stream>>>(src1, dst1, deg1, bsrc1, E1);
    agg_bf16_kernel<<<(N2 + 3) / 4, 256, 0, stream>>>(h, rowptr1, bsrc1, abuf, 768, N2);
    pack1_kernel<<<(N2 + 3) / 4, 256, 0, stream>>>(h, attr, batch1, abuf, N2);
    wcvt_kernel<<<dim3(3, 128), 256, 0, stream>>>(W_l1, W_r1, W_a1, b_l1, b_a1,
                                                  Wt1, bias1, 128);
    gemm_mfma_kernel<false><<<dim3(MP1 / 128, 1), 256, 0, stream>>>(
        abuf, Wt1, bias1, out, N2, 128);
}